// Round 10
// baseline (723.014 us; speedup 1.0000x reference)
//
#include <hip/hip_runtime.h>

// CRF forward (partition fn), B=512, T=512, L=102 (start=100, stop=101).
// R16 (resubmit; round-9 bench was an infra failure): MFMA batched rewrite.
// Key realization: transitions are SHARED across the batch, so each time
// step is a [32x112]x[112x112] f16 GEMM per block of 32 batch rows -- not
// 32 independent matvecs. R13's 265us (~1240cy/step) was a structural floor
// of the matvec shape (26 ds_reads + 51 fma + DPP tail on one serial chain,
// nothing to hide latency under, VGPR cliff at ~132 blocking every widening
// edit: R11/R12/R14/R15).
// Structure: grid 16 blocks x 256 thr (4 waves). Wave wv owns j-tile
// [32wv..32wv+31]. Per step:
//   7x ds_read_b128 (B-frags = Q[k][b] from LDS) -> barrier ->
//   7x chained v_mfma_f32_32x32x16_f16 (A = exp(trans) static, 28 VGPRs) ->
//   D[j][b] (col=lane&31=batch!) * exp(logit) * s_b -> f16 -> 4x ds_write_b64
//   -> barrier.
// Normalization: R15's VERIFIED exponent-trick (power-of-2 scale, int log),
// per batch row, lag-1 via tiny double-buffered LDS table (off-path).
// lens masking: alive = t < len[b] is PER-LANE UNIFORM (lane's col = b);
// dead rows skip the write -> frozen in the single-buffered Q. iacc logged
// only when alive; alive steps form a prefix so lag-1 R is only consumed
// on steps whose predecessor was alive.
// MFMA layouts (HW-verified, guide m74/m89/m101):
//   A: row=l&31, k=(l>>5)*8+i ; B: k=(l>>5)*8+i, col=l&31 ;
//   C/D: col=lane&31, row=(reg&3)+8*(reg>>2)+4*(lane>>5).

typedef _Float16 f16x8 __attribute__((ext_vector_type(8)));
typedef _Float16 f16x4 __attribute__((ext_vector_type(4)));
typedef float f32x2 __attribute__((ext_vector_type(2)));
typedef float f32x16 __attribute__((ext_vector_type(16)));

#define CRF_L 102
#define CRF_START 100
#define CRF_STOP 101
#define LN2F 0.6931471805599453f
#define QS 136   // Q row stride in halves: 272B, 16B-aligned, gcd(68,32)=4

__launch_bounds__(256, 1)
__global__ void crf_forward_kernel(const float* __restrict__ logits,
                                   const float* __restrict__ trans,
                                   const int* __restrict__ lens,
                                   float* __restrict__ out,
                                   int B, int T) {
    const int b0   = blockIdx.x * 32;
    const int tid  = threadIdx.x;        // 0..255
    const int wv   = tid >> 6;           // j-tile 0..3
    const int lane = tid & 63;
    const int bcol = lane & 31;          // this lane's batch column
    const int h    = lane >> 5;          // k/j half-select
    const int J    = 32 * wv + 4 * h;    // E-load / write group base (j)

    __shared__ _Float16 Qsm[32][QS];     // Q[b][j] f16, single-buffered
    __shared__ float    Rb[2][4][64];    // per-step row-sum partials, dbuf

    // ---- init Q = onehot(START) per row; Rb[0] encodes R_init = 1 ----
    for (int i = tid; i < 32 * QS; i += 256) {
        int c = i % QS;
        Qsm[i / QS][c] = (_Float16)((c == CRF_START) ? 1.f : 0.f);
    }
    for (int i = tid; i < 2 * 4 * 64; i += 256) {
        int buf = i >> 8, w = (i >> 6) & 3, l = i & 63;
        Rb[buf][w][l] = (buf == 0 && w == 0 && l < 32) ? 1.f : 0.f;
    }

    // ---- static A-frags: A[j][k] = exp(trans[j][k]), zero-padded ----
    const int  jA   = 32 * wv + bcol;    // A row this lane supplies
    const bool jAok = (jA <= 101);
    const float* trow = trans + (size_t)CRF_L * (jAok ? jA : 0);
    f16x8 a0, a1, a2, a3, a4, a5, a6;
#define MKA(KT, DST) { \
    _Pragma("unroll") \
    for (int i = 0; i < 8; ++i) { \
        int k = (KT)*16 + h*8 + i; \
        float v = (jAok && k <= 101) ? __expf(trow[k]) : 0.f; \
        DST[i] = (_Float16)v; } }
    MKA(0, a0) MKA(1, a1) MKA(2, a2) MKA(3, a3) MKA(4, a4) MKA(5, a5) MKA(6, a6)
#undef MKA

    const int bglob = b0 + bcol;
    const int lenb  = min(lens[bglob], T);
    const float* lgb = logits + (size_t)bglob * (size_t)T * CRF_L;

    // E-load guards (j<=101 only; j>101 cols have D=0 anyway -> load 0)
    const bool g0 = (J      <= 100), g0h = (J      <= 98);
    const bool g1 = (J + 8  <= 100), g1h = (J + 8  <= 98);
    const bool g2 = (J + 16 <= 100), g2h = (J + 16 <= 98);
    const bool g3 = (J + 24 <= 100), g3h = (J + 24 <= 98);

#define LOADE(tt, E) { \
    const float* p_ = lgb + (size_t)(tt) * CRF_L + J; \
    E##0 = g0  ? *(const f32x2*)(p_ + 0)  : (f32x2){0.f, 0.f}; \
    E##1 = g0h ? *(const f32x2*)(p_ + 2)  : (f32x2){0.f, 0.f}; \
    E##2 = g1  ? *(const f32x2*)(p_ + 8)  : (f32x2){0.f, 0.f}; \
    E##3 = g1h ? *(const f32x2*)(p_ + 10) : (f32x2){0.f, 0.f}; \
    E##4 = g2  ? *(const f32x2*)(p_ + 16) : (f32x2){0.f, 0.f}; \
    E##5 = g2h ? *(const f32x2*)(p_ + 18) : (f32x2){0.f, 0.f}; \
    E##6 = g3  ? *(const f32x2*)(p_ + 24) : (f32x2){0.f, 0.f}; \
    E##7 = g3h ? *(const f32x2*)(p_ + 26) : (f32x2){0.f, 0.f}; }

    f32x2 eA0, eA1, eA2, eA3, eA4, eA5, eA6, eA7;   // logits for even t
    f32x2 eB0, eB1, eB2, eB3, eB4, eB5, eB6, eB7;   // logits for odd t
    LOADE(0, eA)
    LOADE(1, eB)

    int iacc = 0;                        // sum of exponent fields (alive steps)
    __syncthreads();                     // init visible

#define RGRP(RG, ELO, EHI, ALIVE, SC, RS) { \
    float e0_ = __expf(ELO[0]), e1_ = __expf(ELO[1]); \
    float e2_ = __expf(EHI[0]), e3_ = __expf(EHI[1]); \
    float q0_ = acc[4*(RG)+0] * e0_ * (SC); \
    float q1_ = acc[4*(RG)+1] * e1_ * (SC); \
    float q2_ = acc[4*(RG)+2] * e2_ * (SC); \
    float q3_ = acc[4*(RG)+3] * e3_ * (SC); \
    RS += (q0_ + q1_) + (q2_ + q3_); \
    if (ALIVE) *(f16x4*)(&Qsm[bcol][J + 8*(RG)]) = \
        (f16x4){(_Float16)q0_, (_Float16)q1_, (_Float16)q2_, (_Float16)q3_}; }

#define STEP(t, E) { \
    const int cur = (t) & 1, nxt = cur ^ 1; \
    const _Float16* qrow = &Qsm[bcol][0]; \
    f16x8 bf0 = *(const f16x8*)(qrow + 0*16 + h*8); \
    f16x8 bf1 = *(const f16x8*)(qrow + 1*16 + h*8); \
    f16x8 bf2 = *(const f16x8*)(qrow + 2*16 + h*8); \
    f16x8 bf3 = *(const f16x8*)(qrow + 3*16 + h*8); \
    f16x8 bf4 = *(const f16x8*)(qrow + 4*16 + h*8); \
    f16x8 bf5 = *(const f16x8*)(qrow + 5*16 + h*8); \
    f16x8 bf6 = *(const f16x8*)(qrow + 6*16 + h*8); \
    float R = ((Rb[cur][0][bcol] + Rb[cur][0][bcol + 32]) \
             + (Rb[cur][1][bcol] + Rb[cur][1][bcol + 32])) \
            + ((Rb[cur][2][bcol] + Rb[cur][2][bcol + 32]) \
             + (Rb[cur][3][bcol] + Rb[cur][3][bcol + 32])); \
    R = fmaxf(R, 1.175494351e-38f); \
    int ef = __builtin_bit_cast(int, R) >> 23; \
    float sc = __builtin_bit_cast(float, (246 - ef) << 23);  /* 2^-(e+8) */ \
    __syncthreads();   /* all B-frag reads complete before any write */ \
    f32x16 acc = {}; \
    acc = __builtin_amdgcn_mfma_f32_32x32x16_f16(a0, bf0, acc, 0, 0, 0); \
    acc = __builtin_amdgcn_mfma_f32_32x32x16_f16(a1, bf1, acc, 0, 0, 0); \
    acc = __builtin_amdgcn_mfma_f32_32x32x16_f16(a2, bf2, acc, 0, 0, 0); \
    acc = __builtin_amdgcn_mfma_f32_32x32x16_f16(a3, bf3, acc, 0, 0, 0); \
    acc = __builtin_amdgcn_mfma_f32_32x32x16_f16(a4, bf4, acc, 0, 0, 0); \
    acc = __builtin_amdgcn_mfma_f32_32x32x16_f16(a5, bf5, acc, 0, 0, 0); \
    acc = __builtin_amdgcn_mfma_f32_32x32x16_f16(a6, bf6, acc, 0, 0, 0); \
    const bool alive = ((t) < lenb); \
    float rsum = 0.f; \
    RGRP(0, E##0, E##1, alive, sc, rsum) \
    RGRP(1, E##2, E##3, alive, sc, rsum) \
    RGRP(2, E##4, E##5, alive, sc, rsum) \
    RGRP(3, E##6, E##7, alive, sc, rsum) \
    Rb[nxt][wv][lane] = rsum; \
    if (alive) iacc += ef; \
    LOADE(min((t) + 2, T - 1), E) \
    __syncthreads(); }

    for (int t = 0; t < T; t += 2) {
        STEP(t, eA)
        STEP(t + 1, eB)
    }
#undef STEP
#undef RGRP
#undef LOADE

    // ---- epilogue: out[b] = ln(sum_j Q[b,j]*exp(trans[STOP,j]))
    //                        + ln2*(iacc - 119*len_b) ----
    if (tid < 32) {
        const _Float16* qr = &Qsm[tid][0];
        const float* tsp = trans + (size_t)CRF_L * CRF_STOP;
        float dot = 0.f;
        for (int j = 0; j < CRF_L; ++j)
            dot += (float)qr[j] * __expf(tsp[j]);
        int bb = b0 + tid;
        int n = min(lens[bb], T);
        out[bb] = __logf(dot) + LN2F * ((float)iacc - 119.0f * (float)n);
    }
}

extern "C" void kernel_launch(void* const* d_in, const int* in_sizes, int n_in,
                              void* d_out, int out_size, void* d_ws, size_t ws_size,
                              hipStream_t stream) {
    const float* logits = (const float*)d_in[0];   // [B, T, L] fp32
    const float* trans  = (const float*)d_in[1];   // [L, L] fp32
    const int*   lens   = (const int*)d_in[2];     // [B] int32
    float* out = (float*)d_out;                    // [B] fp32

    const int B = 512;
    const int T = 512;

    crf_forward_kernel<<<dim3(B / 32), dim3(256), 0, stream>>>(
        logits, trans, lens, out, B, T);
}

// Round 11
// 379.386 us; speedup vs baseline: 1.9057x; 1.9057x over previous
//
#include <hip/hip_runtime.h>

// CRF forward (partition fn), B=512, T=512, L=102 (start=100, stop=101).
// R17: R13 + counted-barrier fix. R16 post-mortem: MFMA batch rewrite has
// 16 blocks -> 0.75% occupancy, step latency 1203ns > R13's 517ns; reverted.
// R13 residual theory: HIP __syncthreads() emits s_waitcnt vmcnt(0) before
// s_barrier (documented ~20% GEMM stall in the guide), so the in-loop lgC
// global prefetch is force-drained EVERY step -> prefetch depth collapses
// to 0 and a full L2/L3 round trip (~400cy) lands on the serial path.
// Fix: raw s_barrier with lgkmcnt(0)-only wait (LDS producer/consumer
// ordering preserved; global loads stay in flight across the barrier).
// Everything else byte-identical to R13 (one-variable experiment).
// Linear recurrence:
//   Q_t[j] = E_j(t) * sum_k Mhat[j,k] Q_{t-1}[k] * rcp(R)*2^-8
// Verification handles: VGPR ~132, LDS ~1KB, conflicts 0, FETCH ~27.5MB.

typedef float f32x2 __attribute__((ext_vector_type(2)));
typedef float f32x4 __attribute__((ext_vector_type(4)));

#define CRF_L 102
#define CRF_RP 104
#define CRF_START 100
#define CRF_STOP 101
#define NEG_BIG (-1.0e30f)
#define LN2F 0.6931471805599453f

#define REP25(X) X(0) X(1) X(2) X(3) X(4) X(5) X(6) X(7) X(8) X(9) X(10) \
                 X(11) X(12) X(13) X(14) X(15) X(16) X(17) X(18) X(19) \
                 X(20) X(21) X(22) X(23) X(24)

template <int CTRL>
__device__ __forceinline__ float dpp_add_step(float x) {
    int xi = __builtin_bit_cast(int, x);
    int yi = __builtin_amdgcn_update_dpp(0, xi, CTRL, 0xf, 0xf, true);
    return x + __builtin_bit_cast(float, yi);
}
__device__ __forceinline__ float wave_sum64(float v) {
    v = dpp_add_step<0x111>(v);  // row_shr:1
    v = dpp_add_step<0x112>(v);  // row_shr:2
    v = dpp_add_step<0x114>(v);  // row_shr:4
    v = dpp_add_step<0x118>(v);  // row_shr:8
    v = dpp_add_step<0x142>(v);  // row_bcast:15
    v = dpp_add_step<0x143>(v);  // row_bcast:31
    return __builtin_bit_cast(float,
        __builtin_amdgcn_readlane(__builtin_bit_cast(int, v), 63));
}

__device__ __forceinline__ f32x2 mk2f(const float* rowp, int k, float rmx) {
    float e0 = __expf(rowp[k + 0] - rmx);
    float e1 = __expf(rowp[k + 1] - rmx);
    return (f32x2){e0, e1};
}

__attribute__((amdgpu_waves_per_eu(1, 1)))
__launch_bounds__(128)
__global__ void crf_forward_kernel(const float* __restrict__ logits,
                                   const float* __restrict__ trans,
                                   const int* __restrict__ lens,
                                   float* __restrict__ out,
                                   int B, int T) {
    const int b    = blockIdx.x;
    const int tid  = threadIdx.x;          // 0..127
    const int wv   = tid >> 6;             // wave 0/1
    const int lane = tid & 63;
    const bool active = (lane < 51);
    const int r    = 51 * wv + lane;       // row 0..101 for active lanes

    // Q double-buffer: [p][0..101]=q values, [p][102]=S_wave0, [p][103]=S_wave1
    __shared__ __align__(16) float Qbuf[2][CRF_RP];

    // ---- init Qbuf[0] = onehot(START); slots = {1,0} (R(0)=1) ----
    if (tid < 51) {
        int i0 = 2 * tid;
        Qbuf[0][i0]     = (i0 == CRF_START) ? 1.f : 0.f;
        Qbuf[0][i0 + 1] = 0.f;
    }
    if (tid == 0) { Qbuf[0][102] = 1.f; Qbuf[0][103] = 0.f; }

    // ---- per-lane row of Mhat = exp(trans[r,:] - rowmax) in 51 f32x2 regs --
    const float* rowp = trans + (size_t)CRF_L * (active ? r : 0);
    float rmx = NEG_BIG;
    #pragma unroll
    for (int k = 0; k < CRF_L; ++k) rmx = fmaxf(rmx, rowp[k]);

#define DECLM(j) f32x2 m##j##a, m##j##b;
    REP25(DECLM)
#undef DECLM
    f32x2 m25a;
#define PACKJ(j) m##j##a = mk2f(rowp, 4*(j), rmx); \
                 m##j##b = mk2f(rowp, 4*(j)+2, rmx);
    REP25(PACKJ)
#undef PACKJ
    m25a = mk2f(rowp, 100, rmx);           // k = 100,101 (no pad pair)

    // E = exp(logit + rmx); inactive lanes forced to 0 via -inf bias
    const float erm = active ? rmx : NEG_BIG;

    const int len = min(lens[b], T);
    const float* lgp = logits + (size_t)b * (size_t)T * (size_t)CRF_L
                              + (active ? r : 0);

    // depth-3 scalar logit prefetch (now genuinely in flight across barriers)
    float lgA = lgp[0];
    float lgB = lgp[(size_t)min(1, T - 1) * CRF_L];
    float lgC = lgp[(size_t)min(2, T - 1) * CRF_L];

    float q    = 0.f;
    float Lacc = 0.f;

    __syncthreads();                       // init visible to both waves (once)

    for (int t = 0; t < len; ++t) {
        const int cur = t & 1;
        const f32x4* P4 = reinterpret_cast<const f32x4*>(&Qbuf[cur][0]);

        // ---- R from pad slots (part of the j=25 b128 we need anyway) ----
        f32x4 qv25 = P4[25];
        float R = qv25[2] + qv25[3];       // S_w0 + S_w1 = sum q_{t-1}
        R = fmaxf(R, 1e-30f);
        float invRs = __builtin_amdgcn_rcpf(R) * 0.00390625f;  // rcp(R)*2^-8
        float l2R = __log2f(R);

        // ---- dot(Mhat[r,:], Q): 26 b128 broadcasts, 51 pk_fma, 8 chains ----
        f32x2 aL0 = {0.f,0.f}, aL1 = {0.f,0.f}, aL2 = {0.f,0.f}, aL3 = {0.f,0.f};
        f32x2 aH0 = {0.f,0.f}, aH1 = {0.f,0.f}, aH2 = {0.f,0.f}, aH3 = {0.f,0.f};
#define DOTQ(j, AL, AH) { f32x4 qv_ = P4[j]; \
        AL = __builtin_elementwise_fma(m##j##a, (f32x2){qv_[0], qv_[1]}, AL); \
        AH = __builtin_elementwise_fma(m##j##b, (f32x2){qv_[2], qv_[3]}, AH); }
        DOTQ(0,  aL0, aH0) DOTQ(1,  aL1, aH1) DOTQ(2,  aL2, aH2) DOTQ(3,  aL3, aH3)
        DOTQ(4,  aL0, aH0) DOTQ(5,  aL1, aH1) DOTQ(6,  aL2, aH2) DOTQ(7,  aL3, aH3)
        DOTQ(8,  aL0, aH0) DOTQ(9,  aL1, aH1) DOTQ(10, aL2, aH2) DOTQ(11, aL3, aH3)
        DOTQ(12, aL0, aH0) DOTQ(13, aL1, aH1) DOTQ(14, aL2, aH2) DOTQ(15, aL3, aH3)
        DOTQ(16, aL0, aH0) DOTQ(17, aL1, aH1) DOTQ(18, aL2, aH2) DOTQ(19, aL3, aH3)
        DOTQ(20, aL0, aH0) DOTQ(21, aL1, aH1) DOTQ(22, aL2, aH2) DOTQ(23, aL3, aH3)
        DOTQ(24, aL0, aH0)
#undef DOTQ
        // group 25: k=100,101 only (pad slots carry S, coeff dropped)
        aL1 = __builtin_elementwise_fma(m25a, (f32x2){qv25[0], qv25[1]}, aL1);

        // ---- shadow: E for this step, prefetch rotate ----
        float ec = __expf(lgA + erm);
        lgA = lgB; lgB = lgC;
        lgC = lgp[(size_t)min(t + 3, T - 1) * CRF_L];

        f32x2 tL = (aL0 + aL1) + (aL2 + aL3);
        f32x2 tH = (aH0 + aH1) + (aH2 + aH3);
        f32x2 tt = tL + tH;
        float dot = tt[0] + tt[1];

        // ---- linear-domain update (factor R*2^8 logged; +8 folded to end) --
        Lacc += l2R;
        q = (dot * ec) * invRs;            // inactive lanes: ec=0 => q=0

        float* Qn = &Qbuf[cur ^ 1][0];
        if (active) Qn[r] = q;

        // wave-partial sum for next step's R (inactive q=0)
        float S = wave_sum64(q);
        if (lane == 0) Qn[102 + wv] = S;

        // ---- counted barrier: LDS ordering only, NO vmcnt drain ----
        // (HIP __syncthreads would emit s_waitcnt vmcnt(0) and force the
        //  lgC prefetch to complete here every step — the ~400cy stall.)
        asm volatile("s_waitcnt lgkmcnt(0)" ::: "memory");
        __builtin_amdgcn_s_barrier();
    }

    // ---- epilogue: out = ln2*(Lacc+8*len) + log(sum_j q_j exp(trans[STOP,j]))
    float tsr = trans[CRF_L * CRF_STOP + (active ? r : 0)];
    float e;
    if (len == 0) {
        e = (active && r == CRF_START) ? __expf(tsr) : 0.f;  // Q0=onehot
    } else {
        e = q * __expf(tsr);               // inactive lanes: q=0
    }
    float sw = wave_sum64(e);
    if (lane == 0) Qbuf[0][wv] = sw;
    __syncthreads();
    if (tid == 0)
        out[b] = LN2F * (Lacc + 8.0f * (float)len)
               + __logf(Qbuf[0][0] + Qbuf[0][1]);
}

extern "C" void kernel_launch(void* const* d_in, const int* in_sizes, int n_in,
                              void* d_out, int out_size, void* d_ws, size_t ws_size,
                              hipStream_t stream) {
    const float* logits = (const float*)d_in[0];   // [B, T, L] fp32
    const float* trans  = (const float*)d_in[1];   // [L, L] fp32
    const int*   lens   = (const int*)d_in[2];     // [B] int32
    float* out = (float*)d_out;                    // [B] fp32

    const int B = 512;
    const int T = 512;

    crf_forward_kernel<<<dim3(B), dim3(128), 0, stream>>>(
        logits, trans, lens, out, B, T);
}

// Round 12
// 354.477 us; speedup vs baseline: 2.0397x; 1.0703x over previous
//
#include <hip/hip_runtime.h>

// CRF forward (partition fn), B=512, T=512, L=102 (start=100, stop=101).
// R18: f16 Q — halve the LDS read stream. Budget that fits ALL data points:
// R13/R17 step = 1245cy == 104 ds_read_b128/CU/step x ~12cy (m134 rate) ->
// the kernel is LDS-READ-BANDWIDTH-bound (every lane re-reads all of Q,
// 416B/lane/step; broadcast reads still cost full pipe time). Explains the
// R9/R10/R17 nulls (saturated throughput pipe is schedule-invariant).
// Fix: Q stored f16 (R8's proven f16-store/f32-acc profile) -> 13 b128
// reads/lane, 52/CU/step ~= 624cy pipe. M = 51 packed half2 regs (52 VGPR,
// far under the ~132 cliff). Dot via 51 fdot2 (R8-validated numerics).
// S pad slots f16: scale bookkeeping self-consistent (logged==applied).
// Group-12 read issued FIRST so the R->rcp/log2 chain starts early.
// R17's lgkmcnt-only barrier retained (vmcnt drain proven harmless but
// the prefetch may matter once LDS pressure halves).
// Linear recurrence:
//   Q_t[j] = E_j(t) * sum_k Mhat[j,k] Q_{t-1}[k] * rcp(R)*2^-8
// Verification handles: VGPR ~100-110, LDS ~1KB, conflicts 0, FETCH 27.5MB.
// Falsifier: dur >= 240us -> LDS-BW theory wrong, suspect fdot2 rate.

typedef _Float16 half2_t __attribute__((ext_vector_type(2)));

#define CRF_L 102
#define CRF_START 100
#define CRF_STOP 101
#define NEG_BIG (-1.0e30f)
#define LN2F 0.6931471805599453f

#define REP12(X) X(0) X(1) X(2) X(3) X(4) X(5) X(6) X(7) X(8) X(9) X(10) X(11)

#define FDOT2(a, b, c) __builtin_amdgcn_fdot2((a), (b), (c), false)

template <int CTRL>
__device__ __forceinline__ float dpp_add_step(float x) {
    int xi = __builtin_bit_cast(int, x);
    int yi = __builtin_amdgcn_update_dpp(0, xi, CTRL, 0xf, 0xf, true);
    return x + __builtin_bit_cast(float, yi);
}
__device__ __forceinline__ float wave_sum64(float v) {
    v = dpp_add_step<0x111>(v);  // row_shr:1
    v = dpp_add_step<0x112>(v);  // row_shr:2
    v = dpp_add_step<0x114>(v);  // row_shr:4
    v = dpp_add_step<0x118>(v);  // row_shr:8
    v = dpp_add_step<0x142>(v);  // row_bcast:15
    v = dpp_add_step<0x143>(v);  // row_bcast:31
    return __builtin_bit_cast(float,
        __builtin_amdgcn_readlane(__builtin_bit_cast(int, v), 63));
}

__device__ __forceinline__ half2_t mk2h(const float* rowp, int k, float rmx) {
    float e0 = __expf(rowp[k + 0] - rmx);
    float e1 = __expf(rowp[k + 1] - rmx);
    return (half2_t){(_Float16)e0, (_Float16)e1};
}

__attribute__((amdgpu_waves_per_eu(1, 1)))
__launch_bounds__(128)
__global__ void crf_forward_kernel(const float* __restrict__ logits,
                                   const float* __restrict__ trans,
                                   const int* __restrict__ lens,
                                   float* __restrict__ out,
                                   int B, int T) {
    const int b    = blockIdx.x;
    const int tid  = threadIdx.x;          // 0..127
    const int wv   = tid >> 6;             // wave 0/1
    const int lane = tid & 63;
    const bool active = (lane < 51);
    const int r    = 51 * wv + lane;       // row 0..101 for active lanes

    // Q double-buffer, f16: [p][0..101]=q, [p][102]=S_w0, [p][103]=S_w1
    __shared__ __align__(16) _Float16 Qbuf[2][104];
    __shared__ float Fin[2];               // epilogue partials (f32)

    // ---- init Qbuf[0] = onehot(START); S slots = {1,0} (R(0)=1) ----
    if (tid < 51) {
        int i0 = 2 * tid;
        Qbuf[0][i0]     = (_Float16)((i0 == CRF_START) ? 1.f : 0.f);
        Qbuf[0][i0 + 1] = (_Float16)0.f;
    }
    if (tid == 0) {
        Qbuf[0][102] = (_Float16)1.f; Qbuf[0][103] = (_Float16)0.f;
    }

    // ---- per-lane row of Mhat = exp(trans[r,:] - rowmax), 51 half2 regs ----
    const float* rowp = trans + (size_t)CRF_L * (active ? r : 0);
    float rmx = NEG_BIG;
    #pragma unroll
    for (int k = 0; k < CRF_L; ++k) rmx = fmaxf(rmx, rowp[k]);

#define DECLM(j) half2_t m##j##_0, m##j##_1, m##j##_2, m##j##_3;
    REP12(DECLM)
#undef DECLM
    half2_t m12_0, m12_1, m12_2;
#define PACKJ(j) \
    m##j##_0 = mk2h(rowp, 8*(j)+0, rmx); m##j##_1 = mk2h(rowp, 8*(j)+2, rmx); \
    m##j##_2 = mk2h(rowp, 8*(j)+4, rmx); m##j##_3 = mk2h(rowp, 8*(j)+6, rmx);
    REP12(PACKJ)
#undef PACKJ
    m12_0 = mk2h(rowp, 96, rmx);
    m12_1 = mk2h(rowp, 98, rmx);
    m12_2 = mk2h(rowp, 100, rmx);          // pads 102,103 never enter the dot

    // E = exp(logit + rmx); inactive lanes forced to 0 via -inf bias
    const float erm = active ? rmx : NEG_BIG;

    const int len = min(lens[b], T);
    const float* lgp = logits + (size_t)b * (size_t)T * (size_t)CRF_L
                              + (active ? r : 0);

    // depth-3 scalar logit prefetch
    float lgA = lgp[0];
    float lgB = lgp[(size_t)min(1, T - 1) * CRF_L];
    float lgC = lgp[(size_t)min(2, T - 1) * CRF_L];

    float q    = 0.f;
    float Lacc = 0.f;

    __syncthreads();                       // init visible to both waves

    for (int t = 0; t < len; ++t) {
        const int cur = t & 1;
        const float4* P4 = reinterpret_cast<const float4*>(&Qbuf[cur][0]);

        // ---- group 12 first: R chain (rcp/log2) starts ASAP ----
        float4 qv12 = P4[12];
        half2_t s01 = __builtin_bit_cast(half2_t, qv12.w);
        float R = (float)s01.x + (float)s01.y;   // S_w0 + S_w1
        R = fmaxf(R, 1e-30f);
        float invRs = __builtin_amdgcn_rcpf(R) * 0.00390625f;  // rcp(R)*2^-8
        float l2R = __log2f(R);

        // ---- dot(Mhat[r,:], Q): 13 b128 broadcasts, 51 fdot2, 4 chains ----
        float c0 = 0.f, c1 = 0.f, c2 = 0.f, c3 = 0.f;
#define DOTQ(j) { float4 qv_ = P4[j]; \
        c0 = FDOT2(m##j##_0, __builtin_bit_cast(half2_t, qv_.x), c0); \
        c1 = FDOT2(m##j##_1, __builtin_bit_cast(half2_t, qv_.y), c1); \
        c2 = FDOT2(m##j##_2, __builtin_bit_cast(half2_t, qv_.z), c2); \
        c3 = FDOT2(m##j##_3, __builtin_bit_cast(half2_t, qv_.w), c3); }
        REP12(DOTQ)
#undef DOTQ
        c0 = FDOT2(m12_0, __builtin_bit_cast(half2_t, qv12.x), c0);
        c1 = FDOT2(m12_1, __builtin_bit_cast(half2_t, qv12.y), c1);
        c2 = FDOT2(m12_2, __builtin_bit_cast(half2_t, qv12.z), c2);

        // ---- shadow: E for this step, prefetch rotate ----
        float ec = __expf(lgA + erm);
        lgA = lgB; lgB = lgC;
        lgC = lgp[(size_t)min(t + 3, T - 1) * CRF_L];

        float dot = (c0 + c1) + (c2 + c3);

        // ---- linear-domain update (factor R*2^8 logged; +8 folded to end) --
        Lacc += l2R;
        q = (dot * ec) * invRs;            // inactive lanes: ec=0 => q=0

        _Float16* Qn = &Qbuf[cur ^ 1][0];
        if (active) Qn[r] = (_Float16)q;

        // wave-partial sum for next step's R (inactive q=0)
        float S = wave_sum64(q);
        if (lane == 0) Qn[102 + wv] = (_Float16)S;

        // ---- counted barrier: LDS ordering only, no vmcnt drain ----
        asm volatile("s_waitcnt lgkmcnt(0)" ::: "memory");
        __builtin_amdgcn_s_barrier();
    }

    // ---- epilogue: out = ln2*(Lacc+8*len) + log(sum_j q_j exp(trans[STOP,j]))
    float tsr = trans[CRF_L * CRF_STOP + (active ? r : 0)];
    float e;
    if (len == 0) {
        e = (active && r == CRF_START) ? __expf(tsr) : 0.f;  // Q0=onehot
    } else {
        e = q * __expf(tsr);               // inactive lanes: q=0
    }
    float sw = wave_sum64(e);
    if (lane == 0) Fin[wv] = sw;
    __syncthreads();
    if (tid == 0)
        out[b] = LN2F * (Lacc + 8.0f * (float)len)
               + __logf(Fin[0] + Fin[1]);
}

extern "C" void kernel_launch(void* const* d_in, const int* in_sizes, int n_in,
                              void* d_out, int out_size, void* d_ws, size_t ws_size,
                              hipStream_t stream) {
    const float* logits = (const float*)d_in[0];   // [B, T, L] fp32
    const float* trans  = (const float*)d_in[1];   // [L, L] fp32
    const int*   lens   = (const int*)d_in[2];     // [B] int32
    float* out = (float*)d_out;                    // [B] fp32

    const int B = 512;
    const int T = 512;

    crf_forward_kernel<<<dim3(B), dim3(128), 0, stream>>>(
        logits, trans, lens, out, B, T);
}